// Round 1
// baseline (880.695 us; speedup 1.0000x reference)
//
#include <hip/hip_runtime.h>
#include <hip/hip_bf16.h>
#include <stdint.h>

// MESRNN fused kernel: edge LSTMs (E=6) + node LSTM + decoder, bf16 MFMA.
// N=131072 agents, H=64, gates=256. One block = 32 agents, 256 threads (4 waves).
#define NA 131072
#define NE 6

typedef short bf16x8 __attribute__((ext_vector_type(8)));
typedef float f32x4 __attribute__((ext_vector_type(4)));

__device__ __forceinline__ unsigned short f2bf(float f) {
    union { float f; unsigned int u; } v; v.f = f;
    unsigned int r = v.u + 0x7fffu + ((v.u >> 16) & 1u);   // RNE
    return (unsigned short)(r >> 16);
}

__device__ __forceinline__ float fsig(float x) {
    return __builtin_amdgcn_rcpf(1.0f + __expf(-x));
}
__device__ __forceinline__ float ftanh(float x) {
    return 2.0f * __builtin_amdgcn_rcpf(1.0f + __expf(-2.0f * x)) - 1.0f;
}

// Pack weights into MFMA B-fragment order (bf16) + combined biases (fp32).
// Edge: B[k][n] = k<64 ? e_wih[e][n][k] : e_whh[e][n][k-64]  (K=128, N=256)
//   layout: wsE[(((e*16+c)*4+s)*64+lane)*8 + j], n=c*16+(lane&15), k=s*32+(lane>>4)*8+j
// Node: B[k][n] = k<448 ? n_wih[n][k] : n_whh[n][k-448]      (K=512, N=256)
//   layout: wsN[(((c*16+s)*64+lane)*8 + j]
__global__ void prep_kernel(
    const float* __restrict__ e_wih, const float* __restrict__ e_whh,
    const float* __restrict__ n_wih, const float* __restrict__ n_whh,
    const float* __restrict__ e_bih, const float* __restrict__ e_bhh,
    const float* __restrict__ n_bih, const float* __restrict__ n_bhh,
    unsigned short* __restrict__ wsE, unsigned short* __restrict__ wsN,
    float* __restrict__ wsBE, float* __restrict__ wsBN)
{
    int gid = blockIdx.x * 256 + threadIdx.x;
    if (gid < 24576) {                       // 6*16*4*64 edge fragment groups
        int L = gid & 63;
        int s = (gid >> 6) & 3;
        int c = (gid >> 8) & 15;
        int e = gid >> 12;
        int n = c * 16 + (L & 15);
        int k0 = s * 32 + (L >> 4) * 8;      // 8-aligned, never straddles 64
        const float* src = (k0 < 64) ? (e_wih + ((size_t)(e * 256 + n)) * 64 + k0)
                                     : (e_whh + ((size_t)(e * 256 + n)) * 64 + (k0 - 64));
        bf16x8 p;
        #pragma unroll
        for (int j = 0; j < 8; ++j) p[j] = (short)f2bf(src[j]);
        *(bf16x8*)(wsE + (size_t)gid * 8) = p;
    } else if (gid < 40960) {                // 16*16*64 node fragment groups
        int g = gid - 24576;
        int L = g & 63;
        int s = (g >> 6) & 15;
        int c = g >> 10;
        int n = c * 16 + (L & 15);
        int k0 = s * 32 + (L >> 4) * 8;      // never straddles 448 (448%8==0)
        const float* src = (k0 < 448) ? (n_wih + (size_t)n * 448 + k0)
                                      : (n_whh + (size_t)n * 64 + (k0 - 448));
        bf16x8 p;
        #pragma unroll
        for (int j = 0; j < 8; ++j) p[j] = (short)f2bf(src[j]);
        *(bf16x8*)(wsN + (size_t)g * 8) = p;
    } else if (gid < 42496) {                // edge biases: bih+bhh, 6*256
        int i = gid - 40960;
        wsBE[i] = e_bih[i] + e_bhh[i];
    } else if (gid < 42752) {                // node biases, 256
        int i = gid - 42496;
        wsBN[i] = n_bih[i] + n_bhh[i];
    }
}

__global__ __launch_bounds__(256, 3) void mesrnn_kernel(
    const float* __restrict__ node_pos,
    const float* __restrict__ edge_inputs,
    const float* __restrict__ edge_h,
    const float* __restrict__ edge_c,
    const float* __restrict__ node_h,
    const float* __restrict__ node_c,
    const float* __restrict__ e_emb_w,
    const float* __restrict__ e_emb_b,
    const float* __restrict__ n_emb_w,
    const float* __restrict__ n_emb_b,
    const float* __restrict__ dec_w,
    const float* __restrict__ dec_b,
    const unsigned short* __restrict__ wsE,
    const unsigned short* __restrict__ wsN,
    const float* __restrict__ wsBE,
    const float* __restrict__ wsBN,
    float* __restrict__ out)
{
    // Row strides padded so consecutive rows shift 4 banks (2-way = free).
    __shared__ unsigned short sA[32][136];   // per-edge A: [emb(64)|h(64)], bf16
    __shared__ unsigned short sC[32][520];   // node A: [emb|6x edge h1|node_h]=512, bf16
    __shared__ float sH1[32][68];            // node h1 fp32 for decoder
    __shared__ float sDec[128];              // dec_w [64][2]

    const int t = threadIdx.x;
    const int lane = t & 63;
    const int w = t >> 6;          // wave 0..3 -> owns gate cols h in [16w,16w+16)
    const int quad = lane >> 4;
    const int l15 = lane & 15;
    const int base = blockIdx.x * 32;

    float* out_pos = out;                                    // [N][2]
    float* out_eh1 = out + (size_t)2 * NA;                   // [E][N][64]
    float* out_ec1 = out_eh1 + (size_t)NE * NA * 64;
    float* out_nh1 = out_ec1 + (size_t)NE * NA * 64;
    float* out_nc1 = out_nh1 + (size_t)NA * 64;

    if (t < 128) sDec[t] = dec_w[t];

    const int fm = t >> 3;            // fill mapping: 32 rows x 8 col-groups
    const int fh0 = (t & 7) * 8;
    const int fgm = base + fm;

    // ---- phase 0: node embedding + node_h -> sC ----
    {
        float x0 = node_pos[(size_t)fgm * 2 + 0];
        float x1 = node_pos[(size_t)fgm * 2 + 1];
        bf16x8 p;
        #pragma unroll
        for (int j = 0; j < 8; ++j) {
            int hh = fh0 + j;
            p[j] = (short)f2bf(ftanh(x0 * n_emb_w[hh] + x1 * n_emb_w[64 + hh] + n_emb_b[hh]));
        }
        *(bf16x8*)&sC[fm][fh0] = p;
        const float4* nh = (const float4*)(node_h + (size_t)fgm * 64 + fh0);
        float4 va = nh[0], vb = nh[1];
        bf16x8 q;
        q[0]=(short)f2bf(va.x); q[1]=(short)f2bf(va.y); q[2]=(short)f2bf(va.z); q[3]=(short)f2bf(va.w);
        q[4]=(short)f2bf(vb.x); q[5]=(short)f2bf(vb.y); q[6]=(short)f2bf(vb.z); q[7]=(short)f2bf(vb.w);
        *(bf16x8*)&sC[fm][448 + fh0] = q;
    }

    const int h = 16 * w + l15;       // this thread's hidden-unit column

    // ---- edge phase: 6 independent LSTM cells ----
    for (int e = 0; e < NE; ++e) {
        {   // fill sA: cols 0..63 = tanh embedding, 64..127 = bf16(edge_h)
            float x0 = edge_inputs[((size_t)e * NA + fgm) * 2 + 0];
            float x1 = edge_inputs[((size_t)e * NA + fgm) * 2 + 1];
            const float* ew = e_emb_w + (size_t)e * 128;
            const float* eb = e_emb_b + (size_t)e * 64;
            bf16x8 p;
            #pragma unroll
            for (int j = 0; j < 8; ++j) {
                int hh = fh0 + j;
                p[j] = (short)f2bf(ftanh(x0 * ew[hh] + x1 * ew[64 + hh] + eb[hh]));
            }
            *(bf16x8*)&sA[fm][fh0] = p;
            const float4* ehp = (const float4*)(edge_h + ((size_t)e * NA + fgm) * 64 + fh0);
            float4 va = ehp[0], vb = ehp[1];
            bf16x8 q;
            q[0]=(short)f2bf(va.x); q[1]=(short)f2bf(va.y); q[2]=(short)f2bf(va.z); q[3]=(short)f2bf(va.w);
            q[4]=(short)f2bf(vb.x); q[5]=(short)f2bf(vb.y); q[6]=(short)f2bf(vb.z); q[7]=(short)f2bf(vb.w);
            *(bf16x8*)&sA[fm][64 + fh0] = q;
        }
        __syncthreads();

        // GEMM: [32x128] @ [128x256]. Wave w owns colTiles {w,w+4,w+8,w+12}
        // => ci maps directly to gate (0=i,1=f,2=g,3=o) for cols h.
        bf16x8 aF0[4], aF1[4];
        #pragma unroll
        for (int s = 0; s < 4; ++s) {
            aF0[s] = *(const bf16x8*)&sA[l15][s * 32 + quad * 8];
            aF1[s] = *(const bf16x8*)&sA[16 + l15][s * 32 + quad * 8];
        }
        f32x4 acc[4][2];
        #pragma unroll
        for (int ci = 0; ci < 4; ++ci) {
            acc[ci][0] = (f32x4){0.f, 0.f, 0.f, 0.f};
            acc[ci][1] = (f32x4){0.f, 0.f, 0.f, 0.f};
        }
        #pragma unroll
        for (int ci = 0; ci < 4; ++ci) {
            int c = w + 4 * ci;
            const unsigned short* bp = wsE + ((((size_t)e * 16 + c) * 4) * 64 + lane) * 8;
            #pragma unroll
            for (int s = 0; s < 4; ++s) {
                bf16x8 bfr = *(const bf16x8*)(bp + (size_t)s * 64 * 8);
                acc[ci][0] = __builtin_amdgcn_mfma_f32_16x16x32_bf16(aF0[s], bfr, acc[ci][0], 0, 0, 0);
                acc[ci][1] = __builtin_amdgcn_mfma_f32_16x16x32_bf16(aF1[s], bfr, acc[ci][1], 0, 0, 0);
            }
        }

        float bi = wsBE[e * 256 + h];
        float bff = wsBE[e * 256 + 64 + h];
        float bg = wsBE[e * 256 + 128 + h];
        float bo = wsBE[e * 256 + 192 + h];
        #pragma unroll
        for (int rt = 0; rt < 2; ++rt) {
            #pragma unroll
            for (int r = 0; r < 4; ++r) {
                int m = rt * 16 + quad * 4 + r;          // C/D row = agent
                size_t idx = ((size_t)e * NA + (base + m)) * 64 + h;
                float c_old = edge_c[idx];
                float iv = fsig(acc[0][rt][r] + bi);
                float fv = fsig(acc[1][rt][r] + bff);
                float gv = ftanh(acc[2][rt][r] + bg);
                float ov = fsig(acc[3][rt][r] + bo);
                float c1 = fv * c_old + iv * gv;
                float h1 = ov * ftanh(c1);
                out_ec1[idx] = c1;
                out_eh1[idx] = h1;
                sC[m][64 + e * 64 + h] = f2bf(h1);       // into concat buffer
            }
        }
        __syncthreads();   // protect sA reuse + sC completeness
    }

    // ---- node phase: [32x512] @ [512x256] ----
    {
        f32x4 acc[4][2];
        #pragma unroll
        for (int ci = 0; ci < 4; ++ci) {
            acc[ci][0] = (f32x4){0.f, 0.f, 0.f, 0.f};
            acc[ci][1] = (f32x4){0.f, 0.f, 0.f, 0.f};
        }
        #pragma unroll 4
        for (int s = 0; s < 16; ++s) {
            bf16x8 a0 = *(const bf16x8*)&sC[l15][s * 32 + quad * 8];
            bf16x8 a1 = *(const bf16x8*)&sC[16 + l15][s * 32 + quad * 8];
            #pragma unroll
            for (int ci = 0; ci < 4; ++ci) {
                int c = w + 4 * ci;
                bf16x8 bfr = *(const bf16x8*)(wsN + (((size_t)c * 16 + s) * 64 + lane) * 8);
                acc[ci][0] = __builtin_amdgcn_mfma_f32_16x16x32_bf16(a0, bfr, acc[ci][0], 0, 0, 0);
                acc[ci][1] = __builtin_amdgcn_mfma_f32_16x16x32_bf16(a1, bfr, acc[ci][1], 0, 0, 0);
            }
        }
        float bi = wsBN[h], bff = wsBN[64 + h], bg = wsBN[128 + h], bo = wsBN[192 + h];
        #pragma unroll
        for (int rt = 0; rt < 2; ++rt) {
            #pragma unroll
            for (int r = 0; r < 4; ++r) {
                int m = rt * 16 + quad * 4 + r;
                size_t idx = (size_t)(base + m) * 64 + h;
                float c_old = node_c[idx];
                float iv = fsig(acc[0][rt][r] + bi);
                float fv = fsig(acc[1][rt][r] + bff);
                float gv = ftanh(acc[2][rt][r] + bg);
                float ov = fsig(acc[3][rt][r] + bo);
                float c1 = fv * c_old + iv * gv;
                float h1 = ov * ftanh(c1);
                out_nc1[idx] = c1;
                out_nh1[idx] = h1;
                sH1[m][h] = h1;
            }
        }
    }
    __syncthreads();

    // ---- decoder: out_pos = node_pos + tanh(h1 @ dec_w + dec_b) ----
    if (t < 64) {
        int m = t >> 1, o = t & 1;
        int gm = base + m;
        float acc = dec_b[o];
        #pragma unroll 8
        for (int hh = 0; hh < 64; ++hh) acc += sH1[m][hh] * sDec[hh * 2 + o];
        out_pos[(size_t)gm * 2 + o] = node_pos[(size_t)gm * 2 + o] + ftanh(acc);
    }
}

extern "C" void kernel_launch(void* const* d_in, const int* in_sizes, int n_in,
                              void* d_out, int out_size, void* d_ws, size_t ws_size,
                              hipStream_t stream) {
    const float* node_pos    = (const float*)d_in[0];
    const float* edge_inputs = (const float*)d_in[1];
    const float* edge_h      = (const float*)d_in[2];
    const float* edge_c      = (const float*)d_in[3];
    const float* node_h      = (const float*)d_in[4];
    const float* node_c      = (const float*)d_in[5];
    const float* e_emb_w     = (const float*)d_in[6];
    const float* e_emb_b     = (const float*)d_in[7];
    const float* e_wih       = (const float*)d_in[8];
    const float* e_whh       = (const float*)d_in[9];
    const float* e_bih       = (const float*)d_in[10];
    const float* e_bhh       = (const float*)d_in[11];
    const float* n_emb_w     = (const float*)d_in[12];
    const float* n_emb_b     = (const float*)d_in[13];
    const float* n_wih       = (const float*)d_in[14];
    const float* n_whh       = (const float*)d_in[15];
    const float* n_bih       = (const float*)d_in[16];
    const float* n_bhh       = (const float*)d_in[17];
    const float* dec_w       = (const float*)d_in[18];
    const float* dec_b       = (const float*)d_in[19];

    // Workspace layout (re-packed every launch; d_ws is re-poisoned):
    //   [0 .. 393216)      wsE: 196608 bf16 edge B-fragments
    //   [393216 .. 655360) wsN: 131072 bf16 node B-fragments
    //   [655360 .. 661504) wsBE: 1536 fp32 combined edge biases
    //   [661504 .. 662528) wsBN: 256 fp32 combined node biases
    unsigned short* wsE = (unsigned short*)d_ws;
    unsigned short* wsN = wsE + 196608;
    float* wsBE = (float*)((char*)d_ws + 655360);
    float* wsBN = wsBE + 1536;

    prep_kernel<<<(42752 + 255) / 256, 256, 0, stream>>>(
        e_wih, e_whh, n_wih, n_whh, e_bih, e_bhh, n_bih, n_bhh,
        wsE, wsN, wsBE, wsBN);

    mesrnn_kernel<<<NA / 32, 256, 0, stream>>>(
        node_pos, edge_inputs, edge_h, edge_c, node_h, node_c,
        e_emb_w, e_emb_b, n_emb_w, n_emb_b, dec_w, dec_b,
        wsE, wsN, wsBE, wsBN, (float*)d_out);
}